// Round 8
// baseline (317.874 us; speedup 1.0000x reference)
//
#include <hip/hip_runtime.h>
#include <hip/hip_cooperative_groups.h>
#include <math.h>

namespace cg = cooperative_groups;

// Output layout (float32, concatenated in reference return order):
//   rendered [128,1,28,28]  @ 0       (100352)
//   mu       [128,64]       @ 100352  (8192)
//   logvar   [128,64]       @ 108544  (8192)
//   cp       [128,2,3,4,2]  @ 116736  (6144)
//   widths   [128,2]        @ 122880  (256)
//   alphas   [128,2]        @ 123136  (256)
#define REND_OFF 0
#define MU_OFF   100352
#define LV_OFF   108544
#define CP_OFF   116736
#define W_OFF    122880
#define A_OFF    123136

// fp32 activation buffers in d_ws (float offsets):
#define A_H1  0        // [128][256]
#define A_H2  32768    // [128][256]
#define A_D1  65536    // [128][512]
#define A_D2  131072   // [128][512]
#define A_PTS 196608   // [128][40]

__device__ __forceinline__ float leakyf(float x) {
    return x >= 0.f ? x : 0.2f * x;
}
__device__ __forceinline__ float seluf(float x) {
    const float sc = 1.0507009873554805f;
    const float al = 1.6732632423543772f;
    return x > 0.f ? sc * x : sc * al * expm1f(x);
}
__device__ __forceinline__ float sigmoidf(float x) {
    return 1.f / (1.f + expf(-x));
}

// Per-thread GEMM core: thread (cl = tid%CT, ks = tid/CT) accumulates
// 8 batch rows for its column over its k-slice; weights via strided scalar
// loads (read-once chip-wide), activations via LDS broadcast float4 pairs.
template<int CT, int KPER>
__device__ __forceinline__ void gcore(const float* __restrict__ cp, int ws,
                                      const float* __restrict__ xs,
                                      float* __restrict__ red, int tid)
{
    constexpr int CTP = CT + 1;
    const int cl = tid % CT, ks = tid / CT;
    const float* p = cp ? cp + (ks * KPER) * ws : nullptr;
    const float* xk = xs + (ks * KPER) * 8;
    float a0=0,a1=0,a2=0,a3=0,a4=0,a5=0,a6=0,a7=0;
    #pragma unroll 4
    for (int kk = 0; kk < KPER; ++kk) {
        float w = p ? p[kk * ws] : 0.f;
        const float4* xv = (const float4*)(xk + kk * 8);
        float4 lo = xv[0], hi = xv[1];
        a0 = fmaf(w, lo.x, a0); a1 = fmaf(w, lo.y, a1);
        a2 = fmaf(w, lo.z, a2); a3 = fmaf(w, lo.w, a3);
        a4 = fmaf(w, hi.x, a4); a5 = fmaf(w, hi.y, a5);
        a6 = fmaf(w, hi.z, a6); a7 = fmaf(w, hi.w, a7);
    }
    red[(ks * 8 + 0) * CTP + cl] = a0;
    red[(ks * 8 + 1) * CTP + cl] = a1;
    red[(ks * 8 + 2) * CTP + cl] = a2;
    red[(ks * 8 + 3) * CTP + cl] = a3;
    red[(ks * 8 + 4) * CTP + cl] = a4;
    red[(ks * 8 + 5) * CTP + cl] = a5;
    red[(ks * 8 + 6) * CTP + cl] = a6;
    red[(ks * 8 + 7) * CTP + cl] = a7;
}

template<int CT, int KS>
__device__ __forceinline__ float rsum(const float* __restrict__ red,
                                      int bb, int cl)
{
    constexpr int CTP = CT + 1;
    float s = 0.f;
    #pragma unroll
    for (int ks = 0; ks < KS; ++ks) s += red[(ks * 8 + bb) * CTP + cl];
    return s;
}

// ---- ONE cooperative kernel: full MLP (weight-stationary, fp32 exact)
// + fused render. Grid 256 x 256. Block (bt = bid>>4, ct = bid&15) computes
// an 8-batch-row x (N/16)-col tile per layer; grid.sync() between layers.
__global__ __launch_bounds__(256) void vae_all(
    const float* __restrict__ x,    const float* __restrict__ eps,
    const float* __restrict__ e_w1, const float* __restrict__ e_b1,
    const float* __restrict__ e_w2, const float* __restrict__ e_b2,
    const float* __restrict__ w_mu, const float* __restrict__ b_mu,
    const float* __restrict__ w_lv, const float* __restrict__ b_lv,
    const float* __restrict__ d_w1, const float* __restrict__ d_b1,
    const float* __restrict__ d_w2, const float* __restrict__ d_b2,
    const float* __restrict__ p_w,  const float* __restrict__ p_b,
    const float* __restrict__ wd_w, const float* __restrict__ wd_b,
    const float* __restrict__ a_w,  const float* __restrict__ a_b,
    float* __restrict__ out,        float* __restrict__ wsf)
{
    cg::grid_group grid = cg::this_grid();
    const int tid = threadIdx.x;
    const int bid = blockIdx.x;
    const int bt  = bid >> 4;          // batch tile: rows bt*8 .. bt*8+7
    const int ct  = bid & 15;          // column tile (16 per layer)
    const int r0  = bt * 8;

    __shared__ __align__(16) float xs[6272];   // [k][bb] interleaved, max K=784
    __shared__ __align__(16) float red[2560];
    __shared__ float2 cur[192];
    __shared__ float  wa[4];

    // ================= L1: K=784, N=256 (CT=16, KS=16, KPER=49) ==========
    for (int i = tid; i < 6272; i += 256) {
        int bb = i / 784, k = i - bb * 784;
        xs[k * 8 + bb] = x[(r0 + bb) * 784 + k];
    }
    __syncthreads();
    {
        int cl = tid % 16;
        gcore<16, 49>(e_w1 + ct * 16 + cl, 256, xs, red, tid);
    }
    __syncthreads();
    if (tid < 128) {
        int bb = tid / 16, cl = tid % 16, cc = ct * 16 + cl;
        float s = rsum<16, 16>(red, bb, cl) + e_b1[cc];
        wsf[A_H1 + (r0 + bb) * 256 + cc] = leakyf(s);
    }
    grid.sync();

    // ================= L2: K=256, N=256 (CT=16, KS=16, KPER=16) ==========
    for (int i = tid; i < 2048; i += 256) {
        int bb = i >> 8, k = i & 255;
        xs[k * 8 + bb] = wsf[A_H1 + (r0 + bb) * 256 + k];
    }
    __syncthreads();
    {
        int cl = tid % 16;
        gcore<16, 16>(e_w2 + ct * 16 + cl, 256, xs, red, tid);
    }
    __syncthreads();
    if (tid < 128) {
        int bb = tid / 16, cl = tid % 16, cc = ct * 16 + cl;
        float s = rsum<16, 16>(red, bb, cl) + e_b2[cc];
        wsf[A_H2 + (r0 + bb) * 256 + cc] = leakyf(s);
    }
    grid.sync();

    // ============ ML: K=256, N=128 mu|lv (CT=8, KS=32, KPER=8) ===========
    for (int i = tid; i < 2048; i += 256) {
        int bb = i >> 8, k = i & 255;
        xs[k * 8 + bb] = wsf[A_H2 + (r0 + bb) * 256 + k];
    }
    __syncthreads();
    {
        int cl = tid % 8, cc = ct * 8 + cl;
        const float* wp = (cc < 64) ? (w_mu + cc) : (w_lv + cc - 64);
        gcore<8, 8>(wp, 64, xs, red, tid);
    }
    __syncthreads();
    if (tid < 64) {
        int bb = tid / 8, cl = tid % 8, cc = ct * 8 + cl;
        float s = rsum<8, 32>(red, bb, cl)
                + ((cc < 64) ? b_mu[cc] : b_lv[cc - 64]);
        out[((cc < 64) ? MU_OFF : LV_OFF) + (r0 + bb) * 64 + (cc & 63)] = s;
    }
    grid.sync();

    // ============ D1: K=64 (z), N=512 (CT=32, KS=8, KPER=8) ==============
    for (int i = tid; i < 512; i += 256) {
        int bb = i >> 6, j = i & 63;
        int row = r0 + bb;
        float mu = out[MU_OFF + row * 64 + j];
        float lv = out[LV_OFF + row * 64 + j];
        xs[j * 8 + bb] = fmaf(eps[row * 64 + j], expf(0.5f * lv), mu);
    }
    __syncthreads();
    {
        int cl = tid % 32;
        gcore<32, 8>(d_w1 + ct * 32 + cl, 512, xs, red, tid);
    }
    __syncthreads();
    {
        int bb = tid / 32, cl = tid % 32, cc = ct * 32 + cl;
        float s = rsum<32, 8>(red, bb, cl) + d_b1[cc];
        wsf[A_D1 + (r0 + bb) * 512 + cc] = seluf(s);
    }
    grid.sync();

    // ============ D2: K=512, N=512 (CT=32, KS=8, KPER=64) ================
    for (int i = tid; i < 4096; i += 256) {
        int bb = i >> 9, k = i & 511;
        xs[k * 8 + bb] = wsf[A_D1 + (r0 + bb) * 512 + k];
    }
    __syncthreads();
    {
        int cl = tid % 32;
        gcore<32, 64>(d_w2 + ct * 32 + cl, 512, xs, red, tid);
    }
    __syncthreads();
    {
        int bb = tid / 32, cl = tid % 32, cc = ct * 32 + cl;
        float s = rsum<32, 8>(red, bb, cl) + d_b2[cc];
        wsf[A_D2 + (r0 + bb) * 512 + cc] = seluf(s);
    }
    grid.sync();

    // ============ H: K=512, N=64 44 live (CT=4, KS=64, KPER=8) ===========
    for (int i = tid; i < 4096; i += 256) {
        int bb = i >> 9, k = i & 511;
        xs[k * 8 + bb] = wsf[A_D2 + (r0 + bb) * 512 + k];
    }
    __syncthreads();
    {
        int cl = tid % 4, cc = ct * 4 + cl;
        const float* wp; int ws;
        if (cc < 40)      { wp = p_w + cc;         ws = 40; }
        else if (cc < 42) { wp = wd_w + (cc - 40); ws = 2;  }
        else if (cc < 44) { wp = a_w + (cc - 42);  ws = 2;  }
        else              { wp = nullptr;          ws = 0;  }
        gcore<4, 8>(wp, ws, xs, red, tid);
    }
    __syncthreads();
    if (tid < 32) {
        int bb = tid / 4, cl = tid % 4, cc = ct * 4 + cl;
        int row = r0 + bb;
        float s = rsum<4, 64>(red, bb, cl);
        if (cc < 40) {
            wsf[A_PTS + row * 40 + cc] = tanhf(s + p_b[cc]) * 12.f + 14.f;
        } else if (cc < 42) {
            out[W_OFF + row * 2 + (cc - 40)] =
                sigmoidf(s + wd_b[cc - 40]) * 2.f + 1.f;
        } else if (cc < 44) {
            out[A_OFF + row * 2 + (cc - 42)] = sigmoidf(s + a_b[cc - 42]);
        }
    }
    grid.sync();

    // ================= RENDER: block (b = bid>>1, half = bid&1) ==========
    {
        const int b    = bid >> 1;
        const int half = bid & 1;
        const float* pg = wsf + A_PTS + b * 40;

        if (tid < 192) {
            int p = tid / 96, m = tid % 96;
            int s = m / 32, t = m % 32;
            float u  = (t + 0.5f) * (1.f / 32.f);
            float v  = 1.f - u;
            float b0 = v * v * v;
            float b1 = 3.f * u * v * v;
            float b2 = 3.f * u * u * v;
            float b3 = u * u * u;
            const float* q = pg + p * 20 + 3 * s * 2;   // pts[p][3s..3s+3][2]
            float cx = b0 * q[0] + b1 * q[2] + b2 * q[4] + b3 * q[6];
            float cy = b0 * q[1] + b1 * q[3] + b2 * q[5] + b3 * q[7];
            cur[tid] = make_float2(cx, cy);
        } else if (tid < 196) {
            int i = tid - 192;
            wa[i] = (i < 2) ? 0.5f * out[W_OFF + b * 2 + i]
                            : out[A_OFF + b * 2 + (i - 2)];
        }
        // cp output scatter (one half-block per image does it)
        if (half == 0 && tid >= 200 && tid < 248) {
            int i = tid - 200;
            int p = i / 24, rem = i % 24;
            int s = rem / 8, kc = rem % 8;
            int k = kc >> 1, c = kc & 1;
            out[CP_OFF + b * 48 + i] = pg[p * 20 + (3 * s + k) * 2 + c];
        }
        __syncthreads();

        const float w0 = wa[0], w1 = wa[1], al0 = wa[2], al1 = wa[3];
        for (int i = tid; i < 392; i += 256) {
            int Y = half * 14 + i / 28, X = i - (i / 28) * 28;
            float px0 = X + 0.25f;
            float py0 = Y + 0.25f;
            float mA[4] = {1e30f, 1e30f, 1e30f, 1e30f};
            float mB[4] = {1e30f, 1e30f, 1e30f, 1e30f};
            #pragma unroll 4
            for (int m = 0; m < 96; ++m) {
                float2 c = cur[m];
                float dx0 = px0 - c.x, dy0 = py0 - c.y;
                float dx1 = dx0 + 0.5f, dy1 = dy0 + 0.5f;
                float xx0 = dx0 * dx0, xx1 = dx1 * dx1;
                float yy0 = dy0 * dy0, yy1 = dy1 * dy1;
                mA[0] = fminf(mA[0], xx0 + yy0);
                mA[1] = fminf(mA[1], xx1 + yy0);
                mA[2] = fminf(mA[2], xx0 + yy1);
                mA[3] = fminf(mA[3], xx1 + yy1);
            }
            #pragma unroll 4
            for (int m = 96; m < 192; ++m) {
                float2 c = cur[m];
                float dx0 = px0 - c.x, dy0 = py0 - c.y;
                float dx1 = dx0 + 0.5f, dy1 = dy0 + 0.5f;
                float xx0 = dx0 * dx0, xx1 = dx1 * dx1;
                float yy0 = dy0 * dy0, yy1 = dy1 * dy1;
                mB[0] = fminf(mB[0], xx0 + yy0);
                mB[1] = fminf(mB[1], xx1 + yy0);
                mB[2] = fminf(mB[2], xx0 + yy1);
                mB[3] = fminf(mB[3], xx1 + yy1);
            }
            float v = 0.f;
            #pragma unroll
            for (int s = 0; s < 4; ++s) {
                float d0 = sqrtf(mA[s] + 1e-12f);
                float d1 = sqrtf(mB[s] + 1e-12f);
                float c0 = al0 / (1.f + expf(-2.f * (w0 - d0)));
                float c1 = al1 / (1.f + expf(-2.f * (w1 - d1)));
                v += (1.f - c0) * (1.f - c1);
            }
            out[REND_OFF + b * 784 + Y * 28 + X] = 1.f - 0.25f * v;
        }
    }
}

extern "C" void kernel_launch(void* const* d_in, const int* in_sizes, int n_in,
                              void* d_out, int out_size, void* d_ws, size_t ws_size,
                              hipStream_t stream) {
    const float* x    = (const float*)d_in[0];
    const float* eps  = (const float*)d_in[1];
    const float* e_w1 = (const float*)d_in[2];
    const float* e_b1 = (const float*)d_in[3];
    const float* e_w2 = (const float*)d_in[4];
    const float* e_b2 = (const float*)d_in[5];
    const float* w_mu = (const float*)d_in[6];
    const float* b_mu = (const float*)d_in[7];
    const float* w_lv = (const float*)d_in[8];
    const float* b_lv = (const float*)d_in[9];
    const float* d_w1 = (const float*)d_in[10];
    const float* d_b1 = (const float*)d_in[11];
    const float* d_w2 = (const float*)d_in[12];
    const float* d_b2 = (const float*)d_in[13];
    const float* p_w  = (const float*)d_in[14];
    const float* p_b  = (const float*)d_in[15];
    const float* wd_w = (const float*)d_in[16];
    const float* wd_b = (const float*)d_in[17];
    const float* a_w  = (const float*)d_in[18];
    const float* a_b  = (const float*)d_in[19];
    float* out = (float*)d_out;
    float* wsf = (float*)d_ws;

    void* args[] = {
        (void*)&x,    (void*)&eps,
        (void*)&e_w1, (void*)&e_b1, (void*)&e_w2, (void*)&e_b2,
        (void*)&w_mu, (void*)&b_mu, (void*)&w_lv, (void*)&b_lv,
        (void*)&d_w1, (void*)&d_b1, (void*)&d_w2, (void*)&d_b2,
        (void*)&p_w,  (void*)&p_b,  (void*)&wd_w, (void*)&wd_b,
        (void*)&a_w,  (void*)&a_b,  (void*)&out,  (void*)&wsf,
    };
    hipLaunchCooperativeKernel((void*)vae_all, dim3(256), dim3(256),
                               args, 0, stream);
}

// Round 9
// 127.236 us; speedup vs baseline: 2.4983x; 2.4983x over previous
//
#include <hip/hip_runtime.h>
#include <hip/hip_bf16.h>
#include <hip/hip_fp16.h>
#include <math.h>

// Output layout (float32, concatenated in reference return order):
//   rendered [128,1,28,28]  @ 0       (100352)
//   mu       [128,64]       @ 100352  (8192)
//   logvar   [128,64]       @ 108544  (8192)
//   cp       [128,2,3,4,2]  @ 116736  (6144)
//   widths   [128,2]        @ 122880  (256)
//   alphas   [128,2]        @ 123136  (256)
#define REND_OFF 0
#define MU_OFF   100352
#define LV_OFF   108544
#define CP_OFF   116736
#define W_OFF    122880
#define A_OFF    123136

// fp16 weight workspace, k-pair COLUMN packed for v_dot2_f32_f16 (r6 layout):
// uint4 q at (k2, j4): q.x = {W[2k2][4j4], W[2k2+1][4j4]} as half2, q.y..q.w
// the next 3 columns. Layer uint4 bases:
#define Q_W1 0       // [400][64]  (K padded 784->800)
#define Q_W2 25600   // [128][64]
#define Q_ML 33792   // [128][32]  (mu|lv fused, N=128)
#define Q_D1 37888   // [32][128]
#define Q_D2 41984   // [256][128]
#define Q_H  74752   // [256][16]  (p|wd|a|pad0, N=64)
#define Q_TOT 78848

// LDS bias array layout (floats):
#define SB_E1 0
#define SB_E2 256
#define SB_MU 512
#define SB_LV 576
#define SB_D1 640
#define SB_D2 1152
#define SB_P  1664
#define SB_WD 1704
#define SB_A  1706
#define SB_TOT 1708

typedef _Float16 half2_t __attribute__((ext_vector_type(2)));

__device__ __forceinline__ float leakyf(float x) {
    return x >= 0.f ? x : 0.2f * x;
}
__device__ __forceinline__ float seluf(float x) {
    const float sc = 1.0507009873554805f;
    const float al = 1.6732632423543772f;
    return x > 0.f ? sc * x : sc * al * expm1f(x);
}
__device__ __forceinline__ float sigmoidf(float x) {
    return 1.f / (1.f + expf(-x));
}
__device__ __forceinline__ unsigned pkh(float a, float b) {
    __half ha = __float2half(a), hb = __float2half(b);
    return (unsigned)__half_as_ushort(ha) | ((unsigned)__half_as_ushort(hb) << 16);
}
__device__ __forceinline__ half2_t as_h2(unsigned u) {
    union { unsigned u; half2_t h; } c; c.u = u; return c.h;
}
__device__ __forceinline__ float dot2(unsigned a, unsigned w, float acc) {
#if __has_builtin(__builtin_amdgcn_fdot2)
    return __builtin_amdgcn_fdot2(as_h2(a), as_h2(w), acc, false);
#else
    half2_t ah = as_h2(a), wh = as_h2(w);
    acc = fmaf((float)ah[0], (float)wh[0], acc);
    return fmaf((float)ah[1], (float)wh[1], acc);
#endif
}

// ---- kernel 0: build k-pair column-packed fp16 weight workspace (== r6) ----
__global__ __launch_bounds__(256) void conv_w(
    const float* __restrict__ e_w1, const float* __restrict__ e_w2,
    const float* __restrict__ w_mu, const float* __restrict__ w_lv,
    const float* __restrict__ d_w1, const float* __restrict__ d_w2,
    const float* __restrict__ p_w,  const float* __restrict__ wd_w,
    const float* __restrict__ a_w,  uint4* __restrict__ wsq)
{
    int t = blockIdx.x * 256 + threadIdx.x;
    if (t >= Q_TOT) return;
    float lo[4], hi[4];
    if (t < Q_W2) {                       // W1: [800pad][256]
        int q = t, k2 = q >> 6, j4 = q & 63;
        int k0 = 2 * k2, c0 = 4 * j4;
        #pragma unroll
        for (int c = 0; c < 4; ++c) {
            lo[c] = (k0     < 784) ? e_w1[k0 * 256 + c0 + c] : 0.f;
            hi[c] = (k0 + 1 < 784) ? e_w1[(k0 + 1) * 256 + c0 + c] : 0.f;
        }
    } else if (t < Q_ML) {                // W2: [256][256]
        int q = t - Q_W2, k2 = q >> 6, j4 = q & 63;
        int k0 = 2 * k2, c0 = 4 * j4;
        #pragma unroll
        for (int c = 0; c < 4; ++c) {
            lo[c] = e_w2[k0 * 256 + c0 + c];
            hi[c] = e_w2[(k0 + 1) * 256 + c0 + c];
        }
    } else if (t < Q_D1) {                // ML: [256][128] = mu|lv
        int q = t - Q_ML, k2 = q >> 5, j4 = q & 31;
        int k0 = 2 * k2, c0 = 4 * j4;
        #pragma unroll
        for (int c = 0; c < 4; ++c) {
            int cc = c0 + c;
            lo[c] = (cc < 64) ? w_mu[k0 * 64 + cc] : w_lv[k0 * 64 + cc - 64];
            hi[c] = (cc < 64) ? w_mu[(k0 + 1) * 64 + cc]
                              : w_lv[(k0 + 1) * 64 + cc - 64];
        }
    } else if (t < Q_D2) {                // D1: [64][512]
        int q = t - Q_D1, k2 = q >> 7, j4 = q & 127;
        int k0 = 2 * k2, c0 = 4 * j4;
        #pragma unroll
        for (int c = 0; c < 4; ++c) {
            lo[c] = d_w1[k0 * 512 + c0 + c];
            hi[c] = d_w1[(k0 + 1) * 512 + c0 + c];
        }
    } else if (t < Q_H) {                 // D2: [512][512]
        int q = t - Q_D2, k2 = q >> 7, j4 = q & 127;
        int k0 = 2 * k2, c0 = 4 * j4;
        #pragma unroll
        for (int c = 0; c < 4; ++c) {
            lo[c] = d_w2[k0 * 512 + c0 + c];
            hi[c] = d_w2[(k0 + 1) * 512 + c0 + c];
        }
    } else {                              // H: [512][64] = p|wd|a|0
        int q = t - Q_H, k2 = q >> 4, j4 = q & 15;
        int k0 = 2 * k2, c0 = 4 * j4;
        #pragma unroll
        for (int c = 0; c < 4; ++c) {
            int cc = c0 + c;
            lo[c] = (cc < 40) ? p_w[k0 * 40 + cc]
                  : (cc < 42) ? wd_w[k0 * 2 + cc - 40]
                  : (cc < 44) ? a_w[k0 * 2 + cc - 42] : 0.f;
            hi[c] = (cc < 40) ? p_w[(k0 + 1) * 40 + cc]
                  : (cc < 42) ? wd_w[(k0 + 1) * 2 + cc - 40]
                  : (cc < 44) ? a_w[(k0 + 1) * 2 + cc - 42] : 0.f;
        }
    }
    uint4 u;
    u.x = pkh(lo[0], hi[0]);
    u.y = pkh(lo[1], hi[1]);
    u.z = pkh(lo[2], hi[2]);
    u.w = pkh(lo[3], hi[3]);
    wsq[t] = u;
}

// ---- wave-local layer GEMM: lane (g = l/JW, j = l%JW) owns cols
// 4*(wave*JW + j)..+3 over k-slice g; butterfly shfl-reduce over g.
// After the call every lane holds the FULL sums for its 4 columns.
template<int N, int JW, int Ks>
__device__ __forceinline__ void hgemm_w(const uint4* __restrict__ wq,
                                        const unsigned* __restrict__ xu,
                                        float (&a)[4], int tid)
{
    const int l  = tid & 63;
    const int wv = tid >> 6;
    const int jg = wv * JW + (l % JW);
    const int g  = l / JW;
    const uint4* wp = wq + (g * Ks) * (N / 4) + jg;
    const unsigned* xp = xu + g * Ks;
    float a0 = 0.f, a1 = 0.f, a2 = 0.f, a3 = 0.f;
    #pragma unroll 8
    for (int kk = 0; kk < Ks; ++kk) {
        uint4 w = wp[kk * (N / 4)];
        unsigned av = xp[kk];
        a0 = dot2(av, w.x, a0);
        a1 = dot2(av, w.y, a1);
        a2 = dot2(av, w.z, a2);
        a3 = dot2(av, w.w, a3);
    }
    #pragma unroll
    for (int m = JW; m < 64; m <<= 1) {
        a0 += __shfl_xor(a0, m);
        a1 += __shfl_xor(a1, m);
        a2 += __shfl_xor(a2, m);
        a3 += __shfl_xor(a3, m);
    }
    a[0] = a0; a[1] = a1; a[2] = a2; a[3] = a3;
}

// ---- fused MLP: 128 blocks x 1024 thr; 1 batch elem per block ----
__global__ __launch_bounds__(1024) void vae_mlp(
    const float* __restrict__ x,    const float* __restrict__ eps,
    const float* __restrict__ e_b1, const float* __restrict__ e_b2,
    const float* __restrict__ b_mu, const float* __restrict__ b_lv,
    const float* __restrict__ d_b1, const float* __restrict__ d_b2,
    const float* __restrict__ p_b,  const float* __restrict__ wd_b,
    const float* __restrict__ a_b,
    const uint4* __restrict__ wsq,  float* __restrict__ out)
{
    const int b   = blockIdx.x;
    const int tid = threadIdx.x;
    const int l   = tid & 63;
    const int wv  = tid >> 6;

    __shared__ __align__(16) unsigned xs[400];    // packed half2 along k
    __shared__ __align__(16) unsigned h1u[128];
    __shared__ __align__(16) unsigned h2u[128];
    __shared__ __align__(16) unsigned zu[32];
    __shared__ __align__(16) unsigned d1u[256];
    __shared__ __align__(16) unsigned d2u[256];
    __shared__ float mulv[128];
    __shared__ float pts[40];
    __shared__ float sb[SB_TOT];                  // all biases

    if (tid < 400) {
        int k0 = 2 * tid;
        float x0 = (k0     < 784) ? x[b * 784 + k0] : 0.f;
        float x1 = (k0 + 1 < 784) ? x[b * 784 + k0 + 1] : 0.f;
        xs[tid] = pkh(x0, x1);
    }
    for (int i = tid; i < SB_TOT; i += 1024) {
        float v;
        if (i < 256)       v = e_b1[i];
        else if (i < 512)  v = e_b2[i - 256];
        else if (i < 576)  v = b_mu[i - 512];
        else if (i < 640)  v = b_lv[i - 576];
        else if (i < 1152) v = d_b1[i - 640];
        else if (i < 1664) v = d_b2[i - 1152];
        else if (i < 1704) v = p_b[i - 1664];
        else if (i < 1706) v = wd_b[i - 1704];
        else               v = a_b[i - 1706];
        sb[i] = v;
    }
    __syncthreads();

    float a[4];

    // encoder L1: K2=400, N=256, JW=4, GW=16
    hgemm_w<256, 4, 25>(wsq + Q_W1, xs, a, tid);
    if (l < 4) {
        int jg = wv * 4 + l, c0 = 4 * jg;
        h1u[2 * jg]     = pkh(leakyf(a[0] + sb[SB_E1 + c0]),
                              leakyf(a[1] + sb[SB_E1 + c0 + 1]));
        h1u[2 * jg + 1] = pkh(leakyf(a[2] + sb[SB_E1 + c0 + 2]),
                              leakyf(a[3] + sb[SB_E1 + c0 + 3]));
    }
    __syncthreads();

    // encoder L2: K2=128, N=256, JW=4, GW=16
    hgemm_w<256, 4, 8>(wsq + Q_W2, h1u, a, tid);
    if (l < 4) {
        int jg = wv * 4 + l, c0 = 4 * jg;
        h2u[2 * jg]     = pkh(leakyf(a[0] + sb[SB_E2 + c0]),
                              leakyf(a[1] + sb[SB_E2 + c0 + 1]));
        h2u[2 * jg + 1] = pkh(leakyf(a[2] + sb[SB_E2 + c0 + 2]),
                              leakyf(a[3] + sb[SB_E2 + c0 + 3]));
    }
    __syncthreads();

    // mu|logvar: K2=128, N=128, JW=2, GW=32
    hgemm_w<128, 2, 4>(wsq + Q_ML, h2u, a, tid);
    if (l < 2) {
        int jg = wv * 2 + l, c0 = 4 * jg;
        #pragma unroll
        for (int e = 0; e < 4; ++e) {
            int cc = c0 + e;
            float v = a[e] + ((cc < 64) ? sb[SB_MU + cc] : sb[SB_LV + cc - 64]);
            mulv[cc] = v;
            out[((cc < 64) ? MU_OFF : LV_OFF) + b * 64 + (cc & 63)] = v;
        }
    }
    __syncthreads();
    if (tid < 32) {
        int j0 = 2 * tid;
        float z0 = fmaf(eps[b * 64 + j0],     expf(0.5f * mulv[64 + j0]),     mulv[j0]);
        float z1 = fmaf(eps[b * 64 + j0 + 1], expf(0.5f * mulv[64 + j0 + 1]), mulv[j0 + 1]);
        zu[tid] = pkh(z0, z1);
    }
    __syncthreads();

    // decoder L1: K2=32, N=512, JW=8, GW=8
    hgemm_w<512, 8, 4>(wsq + Q_D1, zu, a, tid);
    if (l < 8) {
        int jg = wv * 8 + l, c0 = 4 * jg;
        d1u[2 * jg]     = pkh(seluf(a[0] + sb[SB_D1 + c0]),
                              seluf(a[1] + sb[SB_D1 + c0 + 1]));
        d1u[2 * jg + 1] = pkh(seluf(a[2] + sb[SB_D1 + c0 + 2]),
                              seluf(a[3] + sb[SB_D1 + c0 + 3]));
    }
    __syncthreads();

    // decoder L2: K2=256, N=512, JW=8, GW=8
    hgemm_w<512, 8, 32>(wsq + Q_D2, d1u, a, tid);
    if (l < 8) {
        int jg = wv * 8 + l, c0 = 4 * jg;
        d2u[2 * jg]     = pkh(seluf(a[0] + sb[SB_D2 + c0]),
                              seluf(a[1] + sb[SB_D2 + c0 + 1]));
        d2u[2 * jg + 1] = pkh(seluf(a[2] + sb[SB_D2 + c0 + 2]),
                              seluf(a[3] + sb[SB_D2 + c0 + 3]));
    }
    __syncthreads();

    // heads: K2=256, N=64 (44 live), JW=1, GW=64
    hgemm_w<64, 1, 4>(wsq + Q_H, d2u, a, tid);
    if (l == 0) {
        int c0 = 4 * wv;
        #pragma unroll
        for (int e = 0; e < 4; ++e) {
            int cc = c0 + e;
            if (cc < 40) {
                pts[cc] = tanhf(a[e] + sb[SB_P + cc]) * 12.f + 14.f;
            } else if (cc < 42) {
                out[W_OFF + b * 2 + (cc - 40)] =
                    sigmoidf(a[e] + sb[SB_WD + cc - 40]) * 2.f + 1.f;
            } else if (cc < 44) {
                out[A_OFF + b * 2 + (cc - 42)] =
                    sigmoidf(a[e] + sb[SB_A + cc - 42]);
            }
        }
    }
    __syncthreads();

    // scatter cp [P=2,S=3,4,2] from pts [P=2,PPP=10,2]
    if (tid < 48) {
        int p = tid / 24, rem = tid % 24;
        int s = rem / 8, kc = rem % 8;
        int k = kc >> 1, c = kc & 1;
        out[CP_OFF + b * 48 + tid] = pts[p * 20 + (3 * s + k) * 2 + c];
    }
}

// ---- render: grid (128, 4), 256 threads; block (b,q) -> pixel rows 7q.. ----
__global__ __launch_bounds__(256) void vae_render(float* __restrict__ out)
{
    const int b   = blockIdx.x;
    const int q   = blockIdx.y;
    const int tid = threadIdx.x;

    __shared__ float2 cur[192];
    __shared__ float  wa[4];

    if (tid < 192) {
        int p = tid / 96;
        int m = tid % 96;
        int s = m / 32;
        int t = m % 32;
        float u  = (t + 0.5f) * (1.f / 32.f);
        float v  = 1.f - u;
        float b0 = v * v * v;
        float b1 = 3.f * u * v * v;
        float b2 = 3.f * u * u * v;
        float b3 = u * u * u;
        const float* cp = out + CP_OFF + b * 48 + p * 24 + s * 8;
        float cx = b0 * cp[0] + b1 * cp[2] + b2 * cp[4] + b3 * cp[6];
        float cy = b0 * cp[1] + b1 * cp[3] + b2 * cp[5] + b3 * cp[7];
        cur[tid] = make_float2(cx, cy);
    } else if (tid < 196) {
        int i = tid - 192;
        wa[i] = (i < 2) ? 0.5f * out[W_OFF + b * 2 + i]
                        : out[A_OFF + b * 2 + (i - 2)];
    }
    __syncthreads();

    if (tid < 196) {
        int Y = tid / 28, X = tid - Y * 28;
        float px0 = X + 0.25f;
        float py0 = (7 * q + Y) + 0.25f;

        float mA[4] = {1e30f, 1e30f, 1e30f, 1e30f};
        float mB[4] = {1e30f, 1e30f, 1e30f, 1e30f};
        #pragma unroll 4
        for (int m = 0; m < 96; ++m) {
            float2 c = cur[m];
            float dx0 = px0 - c.x, dy0 = py0 - c.y;
            float dx1 = dx0 + 0.5f, dy1 = dy0 + 0.5f;
            float xx0 = dx0 * dx0, xx1 = dx1 * dx1;
            float yy0 = dy0 * dy0, yy1 = dy1 * dy1;
            mA[0] = fminf(mA[0], xx0 + yy0);
            mA[1] = fminf(mA[1], xx1 + yy0);
            mA[2] = fminf(mA[2], xx0 + yy1);
            mA[3] = fminf(mA[3], xx1 + yy1);
        }
        #pragma unroll 4
        for (int m = 96; m < 192; ++m) {
            float2 c = cur[m];
            float dx0 = px0 - c.x, dy0 = py0 - c.y;
            float dx1 = dx0 + 0.5f, dy1 = dy0 + 0.5f;
            float xx0 = dx0 * dx0, xx1 = dx1 * dx1;
            float yy0 = dy0 * dy0, yy1 = dy1 * dy1;
            mB[0] = fminf(mB[0], xx0 + yy0);
            mB[1] = fminf(mB[1], xx1 + yy0);
            mB[2] = fminf(mB[2], xx0 + yy1);
            mB[3] = fminf(mB[3], xx1 + yy1);
        }

        const float w0 = wa[0], w1 = wa[1], a0 = wa[2], a1 = wa[3];
        float v = 0.f;
        #pragma unroll
        for (int s = 0; s < 4; ++s) {
            float d0 = sqrtf(mA[s] + 1e-12f);
            float d1 = sqrtf(mB[s] + 1e-12f);
            float c0 = a0 / (1.f + expf(-2.f * (w0 - d0)));
            float c1 = a1 / (1.f + expf(-2.f * (w1 - d1)));
            v += (1.f - c0) * (1.f - c1);
        }
        out[REND_OFF + b * 784 + (7 * q + Y) * 28 + X] = 1.f - 0.25f * v;
    }
}

extern "C" void kernel_launch(void* const* d_in, const int* in_sizes, int n_in,
                              void* d_out, int out_size, void* d_ws, size_t ws_size,
                              hipStream_t stream) {
    const float* x    = (const float*)d_in[0];
    const float* eps  = (const float*)d_in[1];
    const float* e_w1 = (const float*)d_in[2];
    const float* e_b1 = (const float*)d_in[3];
    const float* e_w2 = (const float*)d_in[4];
    const float* e_b2 = (const float*)d_in[5];
    const float* w_mu = (const float*)d_in[6];
    const float* b_mu = (const float*)d_in[7];
    const float* w_lv = (const float*)d_in[8];
    const float* b_lv = (const float*)d_in[9];
    const float* d_w1 = (const float*)d_in[10];
    const float* d_b1 = (const float*)d_in[11];
    const float* d_w2 = (const float*)d_in[12];
    const float* d_b2 = (const float*)d_in[13];
    const float* p_w  = (const float*)d_in[14];
    const float* p_b  = (const float*)d_in[15];
    const float* wd_w = (const float*)d_in[16];
    const float* wd_b = (const float*)d_in[17];
    const float* a_w  = (const float*)d_in[18];
    const float* a_b  = (const float*)d_in[19];
    float* out = (float*)d_out;
    uint4* wsq = (uint4*)d_ws;

    hipLaunchKernelGGL(conv_w, dim3((Q_TOT + 255) / 256), dim3(256), 0, stream,
                       e_w1, e_w2, w_mu, w_lv, d_w1, d_w2, p_w, wd_w, a_w, wsq);
    hipLaunchKernelGGL(vae_mlp, dim3(128), dim3(1024), 0, stream,
                       x, eps, e_b1, e_b2, b_mu, b_lv, d_b1, d_b2,
                       p_b, wd_b, a_b, wsq, out);
    hipLaunchKernelGGL(vae_render, dim3(128, 4), dim3(256), 0, stream, out);
}